// Round 3
// baseline (355.255 us; speedup 1.0000x reference)
//
#include <hip/hip_runtime.h>
#include <hip/hip_bf16.h>

// MaskedRoIAlign: out[k,c,ph,pw] = mean over SR*SR bilinear samples of
// (features[b_k] * masks[k]) with torchvision RoIAlign edge handling.
// N=2, C=256, H=W=64, K=64, PH=PW=7, SCALE=0.25, SR=2. Output fp32.
//
// R2: R1's row-range streaming + COLUMN trimming. Phase 1 streams only the
// float4-aligned column window [xlo&~3 .. xhi|3] of rows [ylo..yhi] for
// features & masks (coalesced), multiplies, stores product to LDS with
// compact pitch w4. Phase 2 bilinear-gathers 16 corners per bin from LDS.
// Cuts streamed bytes ~2.2x vs full-width rows (avg span ~112B vs 256B).
// NOTE: bench dur_us carries ~305us of harness reset (1GB d_ws poison fill
// ~160us + input restore copies); kernel-attributed time is the residual.

constexpr int N_ = 2, C_ = 256, H_ = 64, W_ = 64;
constexpr int K_ = 64, PH_ = 7, PW_ = 7, SR_ = 2;
constexpr float SCALE_ = 0.25f;
constexpr int CG = 2;          // channels per block
constexpr int BT = 128;        // 2 waves; phase2: wave i -> channel i

__global__ __launch_bounds__(BT)
void masked_roialign_lds(const float* __restrict__ features,
                         const float* __restrict__ boxes,
                         const float* __restrict__ masks,
                         float* __restrict__ out) {
    __shared__ float prod[CG][H_ * W_];    // worst case 64x64 per ch; 32 KB

    const int k  = blockIdx.x;             // box
    const int cg = blockIdx.y;             // channel group of CG
    const int t  = threadIdx.x;

    // Box parameters (uniform per block).
    const float* bx = boxes + k * 5;
    const int   b  = (int)bx[0];
    const float x1 = bx[1] * SCALE_;
    const float y1 = bx[2] * SCALE_;
    const float x2 = bx[3] * SCALE_;
    const float y2 = bx[4] * SCALE_;
    const float roi_w = fmaxf(x2 - x1, 1.0f);
    const float roi_h = fmaxf(y2 - y1, 1.0f);
    const float bin_w = roi_w * (1.0f / PW_);
    const float bin_h = roi_h * (1.0f / PH_);

    // Sample extent (pre-clamp): y in [y1+0.25*bh, y1+6.75*bh], same for x.
    const float ymin_c = fminf(fmaxf(y1 + 0.25f * bin_h, 0.0f), (float)(H_ - 1));
    const float ymax_c = fminf(fmaxf(y1 + 6.75f * bin_h, 0.0f), (float)(H_ - 1));
    const int ylo   = (int)ymin_c;
    const int yhi   = min((int)ymax_c + 1, H_ - 1);
    const int nrows = yhi - ylo + 1;                 // 1..64

    const float xmin_c = fminf(fmaxf(x1 + 0.25f * bin_w, 0.0f), (float)(W_ - 1));
    const float xmax_c = fminf(fmaxf(x1 + 6.75f * bin_w, 0.0f), (float)(W_ - 1));
    const int xlo = (int)xmin_c;
    const int xhi = min((int)xmax_c + 1, W_ - 1);
    const int c0  = xlo >> 2;                        // first float4 column
    const int c1  = xhi >> 2;                        // last float4 column
    const int nf4 = c1 - c0 + 1;                     // 1..16 float4 cols
    const int w4  = nf4 << 2;                        // LDS pitch (floats)
    const int xbase = c0 << 2;                       // first stored column

    // Phase 1: stream trimmed window, product -> LDS. 8 cols x 16 rows map.
    const int tx = t & 7;                            // float4 column lane
    const int ty = t >> 3;                           // row lane (16)
#pragma unroll
    for (int cl = 0; cl < CG; ++cl) {
        const int c = cg * CG + cl;
        const float* fb = features + ((size_t)b * C_ + c) * (H_ * W_);
        const float* mb = masks    + ((size_t)k * C_ + c) * (H_ * W_);
        for (int r = ty; r < nrows; r += 16) {
            const float4* frow = (const float4*)(fb + (ylo + r) * W_) + c0;
            const float4* mrow = (const float4*)(mb + (ylo + r) * W_) + c0;
            float4* prow = (float4*)(&prod[cl][r * w4]);   // w4 % 4 == 0
            for (int col = tx; col < nf4; col += 8) {
                const float4 fv = frow[col];
                const float4 mv = mrow[col];
                prow[col] = make_float4(fv.x * mv.x, fv.y * mv.y,
                                        fv.z * mv.z, fv.w * mv.w);
            }
        }
    }
    __syncthreads();

    // Phase 2: wave cl handles channel cg*CG+cl; lane = output bin (49/64).
    const int cl  = t >> 6;
    const int bin = t & 63;
    if (bin >= PH_ * PW_) return;
    const int ph = bin / PW_;
    const int pw = bin - ph * PW_;

    const float* __restrict__ p = prod[cl];

    float acc = 0.0f;
#pragma unroll
    for (int iy = 0; iy < SR_; ++iy) {
        const float y  = y1 + ((float)ph + ((float)iy + 0.5f) * 0.5f) * bin_h;
        const bool  vy = (y >= -1.0f) && (y <= (float)H_);
        const float yc = fminf(fmaxf(y, 0.0f), (float)(H_ - 1));
        const int   yl = (int)yc;
        const int   yh = min(yl + 1, H_ - 1);
        const float ly = yc - (float)yl;
        const float hy = 1.0f - ly;
        const int   rl = (yl - ylo) * w4;
        const int   rh = (yh - ylo) * w4;
#pragma unroll
        for (int ix = 0; ix < SR_; ++ix) {
            const float x  = x1 + ((float)pw + ((float)ix + 0.5f) * 0.5f) * bin_w;
            const bool  vx = (x >= -1.0f) && (x <= (float)W_);
            const float xc = fminf(fmaxf(x, 0.0f), (float)(W_ - 1));
            const int   xl = (int)xc;
            const int   xh = min(xl + 1, W_ - 1);
            const float lx = xc - (float)xl;
            const float hx = 1.0f - lx;

            const float v00 = p[rl + xl - xbase];
            const float v01 = p[rl + xh - xbase];
            const float v10 = p[rh + xl - xbase];
            const float v11 = p[rh + xh - xbase];
            const float val = hy * hx * v00 + hy * lx * v01
                            + ly * hx * v10 + ly * lx * v11;
            acc += (vy && vx) ? val : 0.0f;
        }
    }
    const int c = cg * CG + cl;
    out[(((size_t)k * C_ + c) * PH_ + ph) * PW_ + pw] = acc * 0.25f;
}

extern "C" void kernel_launch(void* const* d_in, const int* in_sizes, int n_in,
                              void* d_out, int out_size, void* d_ws, size_t ws_size,
                              hipStream_t stream) {
    const float* features = (const float*)d_in[0];  // [2,256,64,64]
    const float* boxes    = (const float*)d_in[1];  // [64,5]
    const float* masks    = (const float*)d_in[2];  // [64,256,64,64]
    float* out            = (float*)d_out;          // [64,256,7,7]

    dim3 grid(K_, C_ / CG);   // 64 x 128 blocks
    dim3 block(BT);
    masked_roialign_lds<<<grid, block, 0, stream>>>(features, boxes, masks, out);
}

// Round 4
// 338.162 us; speedup vs baseline: 1.0505x; 1.0505x over previous
//
#include <hip/hip_runtime.h>
#include <hip/hip_bf16.h>
#include <hip/hip_fp16.h>

// MaskedRoIAlign: out[k,c,ph,pw] = mean over SR*SR bilinear samples of
// (features[b_k] * masks[k]) with torchvision RoIAlign edge handling.
// N=2, C=256, H=W=64, K=64, PH=PW=7, SCALE=0.25, SR=2. Output fp32.
//
// R3: R1 streaming structure with occupancy doubled via fp16 LDS product.
//  - LDS 16 KB/block (2 ch x 4096 halves) -> 10 blocks/CU x 2 waves = 20
//    waves/CU (vs 10 for fp32 LDS). Phase-1 HBM latency now hidden.
//  - No column trim (128B line granularity makes it traffic-neutral; R2
//    showed it only adds VALU). Row-range trim kept (rows are 256B).
//  - Fixed 16x8 thread map: each thread does nrows/8 iterations, one
//    float4 column, zero divergent bounds.
//  - fp16 product error ~4e-3 absmax (|prod|<~5), threshold is 4.5e-2.
// Bench note: dur_us carries ~250-300us of harness reset (1.07GB d_ws
// poison fill ~161us + ~264MB input restore); kernel is the residual.

constexpr int N_ = 2, C_ = 256, H_ = 64, W_ = 64;
constexpr int K_ = 64, PH_ = 7, PW_ = 7, SR_ = 2;
constexpr float SCALE_ = 0.25f;
constexpr int CG = 2;          // channels per block
constexpr int BT = 128;        // 2 waves; phase2: wave i -> channel i

__global__ __launch_bounds__(BT)
void masked_roialign_h16(const float* __restrict__ features,
                         const float* __restrict__ boxes,
                         const float* __restrict__ masks,
                         float* __restrict__ out) {
    __shared__ __half prod[CG][H_ * W_];   // 2 x 8 KB = 16 KB

    const int k  = blockIdx.x;             // box
    const int cg = blockIdx.y;             // channel group of CG
    const int t  = threadIdx.x;

    // Box parameters (uniform per block).
    const float* bx = boxes + k * 5;
    const int   b  = (int)bx[0];
    const float x1 = bx[1] * SCALE_;
    const float y1 = bx[2] * SCALE_;
    const float x2 = bx[3] * SCALE_;
    const float y2 = bx[4] * SCALE_;
    const float roi_w = fmaxf(x2 - x1, 1.0f);
    const float roi_h = fmaxf(y2 - y1, 1.0f);
    const float bin_w = roi_w * (1.0f / PW_);
    const float bin_h = roi_h * (1.0f / PH_);

    // Row range covering all clamped sample rows and +1 neighbors.
    const float ymin_c = fminf(fmaxf(y1 + 0.25f * bin_h, 0.0f), (float)(H_ - 1));
    const float ymax_c = fminf(fmaxf(y1 + 6.75f * bin_h, 0.0f), (float)(H_ - 1));
    const int ylo   = (int)ymin_c;
    const int yhi   = min((int)ymax_c + 1, H_ - 1);
    const int nrows = yhi - ylo + 1;                 // 1..64

    // Phase 1: stream full-width rows [ylo..yhi]; product -> fp16 LDS.
    // Thread map: tx = float4 column (16), ty = row lane (8).
    const int tx = (t & 15) << 2;                    // float column 0..60
    const int ty = t >> 4;                           // 0..7
#pragma unroll
    for (int cl = 0; cl < CG; ++cl) {
        const int c = cg * CG + cl;
        const float* fb = features + ((size_t)b * C_ + c) * (H_ * W_);
        const float* mb = masks    + ((size_t)k * C_ + c) * (H_ * W_);
        for (int r = ty; r < nrows; r += 8) {
            const int row = ylo + r;
            const float4 fv = *(const float4*)(fb + row * W_ + tx);
            const float4 mv = *(const float4*)(mb + row * W_ + tx);
            __half2* dst = (__half2*)&prod[cl][row * W_ + tx];
            dst[0] = __floats2half2_rn(fv.x * mv.x, fv.y * mv.y);
            dst[1] = __floats2half2_rn(fv.z * mv.z, fv.w * mv.w);
        }
    }
    __syncthreads();

    // Phase 2: wave cl handles channel cg*CG+cl; lane = output bin (49/64).
    const int cl  = t >> 6;
    const int bin = t & 63;
    if (bin >= PH_ * PW_) return;
    const int ph = bin / PW_;
    const int pw = bin - ph * PW_;

    const __half* __restrict__ p = prod[cl];

    float acc = 0.0f;
#pragma unroll
    for (int iy = 0; iy < SR_; ++iy) {
        const float y  = y1 + ((float)ph + ((float)iy + 0.5f) * 0.5f) * bin_h;
        const bool  vy = (y >= -1.0f) && (y <= (float)H_);
        const float yc = fminf(fmaxf(y, 0.0f), (float)(H_ - 1));
        const int   yl = (int)yc;
        const int   yh = min(yl + 1, H_ - 1);
        const float ly = yc - (float)yl;
        const float hy = 1.0f - ly;
        const int   rl = yl * W_;
        const int   rh = yh * W_;
#pragma unroll
        for (int ix = 0; ix < SR_; ++ix) {
            const float x  = x1 + ((float)pw + ((float)ix + 0.5f) * 0.5f) * bin_w;
            const bool  vx = (x >= -1.0f) && (x <= (float)W_);
            const float xc = fminf(fmaxf(x, 0.0f), (float)(W_ - 1));
            const int   xl = (int)xc;
            const int   xh = min(xl + 1, W_ - 1);
            const float lx = xc - (float)xl;
            const float hx = 1.0f - lx;

            const float v00 = __half2float(p[rl + xl]);
            const float v01 = __half2float(p[rl + xh]);
            const float v10 = __half2float(p[rh + xl]);
            const float v11 = __half2float(p[rh + xh]);
            const float val = hy * hx * v00 + hy * lx * v01
                            + ly * hx * v10 + ly * lx * v11;
            acc += (vy && vx) ? val : 0.0f;
        }
    }
    const int c = cg * CG + cl;
    out[(((size_t)k * C_ + c) * PH_ + ph) * PW_ + pw] = acc * 0.25f;
}

extern "C" void kernel_launch(void* const* d_in, const int* in_sizes, int n_in,
                              void* d_out, int out_size, void* d_ws, size_t ws_size,
                              hipStream_t stream) {
    const float* features = (const float*)d_in[0];  // [2,256,64,64]
    const float* boxes    = (const float*)d_in[1];  // [64,5]
    const float* masks    = (const float*)d_in[2];  // [64,256,64,64]
    float* out            = (float*)d_out;          // [64,256,7,7]

    dim3 grid(K_, C_ / CG);   // 64 x 128 blocks
    dim3 block(BT);
    masked_roialign_h16<<<grid, block, 0, stream>>>(features, boxes, masks, out);
}

// Round 5
// 332.354 us; speedup vs baseline: 1.0689x; 1.0175x over previous
//
#include <hip/hip_runtime.h>
#include <hip/hip_bf16.h>
#include <hip/hip_fp16.h>

// MaskedRoIAlign: out[k,c,ph,pw] = mean over SR*SR bilinear samples of
// (features[b_k] * masks[k]) with torchvision RoIAlign edge handling.
// N=2, C=256, H=W=64, K=64, PH=PW=7, SCALE=0.25, SR=2. Output fp32.
//
// R4: R3 (fp16-LDS product, 20 waves/CU) +
//  - nontemporal loads for the read-once mask stream (~97MB): keeps the
//    8MB features working set L2-resident instead of being thrashed.
//  - phase-1 loop restructured: all 4 loads (f0,m0,f1,m1) per row issue
//    back-to-back before the LDS-write dependency -> 4 outstanding VMEM
//    per iteration instead of 2.
// Traffic floor: mask ~97MB HBM + features ~97MB (L2) + 3MB write -> ~20us
// kernel. Bench dur_us carries ~300us fixed harness reset (1.07GB ws
// poison fill ~161us + ~264MB input restore); kernel is the residual.

constexpr int N_ = 2, C_ = 256, H_ = 64, W_ = 64;
constexpr int K_ = 64, PH_ = 7, PW_ = 7, SR_ = 2;
constexpr float SCALE_ = 0.25f;
constexpr int CG = 2;          // channels per block
constexpr int BT = 128;        // 2 waves; phase2: wave i -> channel i

typedef float vf4 __attribute__((ext_vector_type(4)));  // native vector for
                                                        // __builtin_nontemporal_load

__global__ __launch_bounds__(BT)
void masked_roialign_h16(const float* __restrict__ features,
                         const float* __restrict__ boxes,
                         const float* __restrict__ masks,
                         float* __restrict__ out) {
    __shared__ __half prod[CG][H_ * W_];   // 2 x 8 KB = 16 KB

    const int k  = blockIdx.x;             // box (fast grid axis: 64 consecutive
    const int cg = blockIdx.y;             // blocks share feature channels -> L2)
    const int t  = threadIdx.x;

    // Box parameters (uniform per block).
    const float* bx = boxes + k * 5;
    const int   b  = (int)bx[0];
    const float x1 = bx[1] * SCALE_;
    const float y1 = bx[2] * SCALE_;
    const float x2 = bx[3] * SCALE_;
    const float y2 = bx[4] * SCALE_;
    const float roi_w = fmaxf(x2 - x1, 1.0f);
    const float roi_h = fmaxf(y2 - y1, 1.0f);
    const float bin_w = roi_w * (1.0f / PW_);
    const float bin_h = roi_h * (1.0f / PH_);

    // Row range covering all clamped sample rows and +1 neighbors.
    const float ymin_c = fminf(fmaxf(y1 + 0.25f * bin_h, 0.0f), (float)(H_ - 1));
    const float ymax_c = fminf(fmaxf(y1 + 6.75f * bin_h, 0.0f), (float)(H_ - 1));
    const int ylo   = (int)ymin_c;
    const int yhi   = min((int)ymax_c + 1, H_ - 1);
    const int nrows = yhi - ylo + 1;                 // 1..64

    // Phase 1: stream full-width rows [ylo..yhi]; product -> fp16 LDS.
    // Thread map: tx = float4 column (16), ty = row lane (8). Both channels
    // loaded per iteration so 4 VMEM ops are in flight before the LDS write.
    {
        const int tx = (t & 15) << 2;                // float column 0..60
        const int ty = t >> 4;                       // 0..7
        const int c0 = cg * CG;
        const float* fb0 = features + ((size_t)b * C_ + c0) * (H_ * W_);
        const float* mb0 = masks    + ((size_t)k * C_ + c0) * (H_ * W_);
        for (int r = ty; r < nrows; r += 8) {
            const int off = (ylo + r) * W_ + tx;
            const vf4 fv0 = *(const vf4*)(fb0 + off);
            const vf4 mv0 = __builtin_nontemporal_load((const vf4*)(mb0 + off));
            const vf4 fv1 = *(const vf4*)(fb0 + (H_ * W_) + off);
            const vf4 mv1 = __builtin_nontemporal_load((const vf4*)(mb0 + (size_t)(H_ * W_) + off));
            __half2* d0 = (__half2*)&prod[0][off - 0];      // same off layout
            d0[0] = __floats2half2_rn(fv0.x * mv0.x, fv0.y * mv0.y);
            d0[1] = __floats2half2_rn(fv0.z * mv0.z, fv0.w * mv0.w);
            __half2* d1 = (__half2*)&prod[1][off];
            d1[0] = __floats2half2_rn(fv1.x * mv1.x, fv1.y * mv1.y);
            d1[1] = __floats2half2_rn(fv1.z * mv1.z, fv1.w * mv1.w);
        }
    }
    __syncthreads();

    // Phase 2: wave cl handles channel cg*CG+cl; lane = output bin (49/64).
    const int cl  = t >> 6;
    const int bin = t & 63;
    if (bin >= PH_ * PW_) return;
    const int ph = bin / PW_;
    const int pw = bin - ph * PW_;

    const __half* __restrict__ p = prod[cl];

    float acc = 0.0f;
#pragma unroll
    for (int iy = 0; iy < SR_; ++iy) {
        const float y  = y1 + ((float)ph + ((float)iy + 0.5f) * 0.5f) * bin_h;
        const bool  vy = (y >= -1.0f) && (y <= (float)H_);
        const float yc = fminf(fmaxf(y, 0.0f), (float)(H_ - 1));
        const int   yl = (int)yc;
        const int   yh = min(yl + 1, H_ - 1);
        const float ly = yc - (float)yl;
        const float hy = 1.0f - ly;
        const int   rl = yl * W_;
        const int   rh = yh * W_;
#pragma unroll
        for (int ix = 0; ix < SR_; ++ix) {
            const float x  = x1 + ((float)pw + ((float)ix + 0.5f) * 0.5f) * bin_w;
            const bool  vx = (x >= -1.0f) && (x <= (float)W_);
            const float xc = fminf(fmaxf(x, 0.0f), (float)(W_ - 1));
            const int   xl = (int)xc;
            const int   xh = min(xl + 1, W_ - 1);
            const float lx = xc - (float)xl;
            const float hx = 1.0f - lx;

            const float v00 = __half2float(p[rl + xl]);
            const float v01 = __half2float(p[rl + xh]);
            const float v10 = __half2float(p[rh + xl]);
            const float v11 = __half2float(p[rh + xh]);
            const float val = hy * hx * v00 + hy * lx * v01
                            + ly * hx * v10 + ly * lx * v11;
            acc += (vy && vx) ? val : 0.0f;
        }
    }
    const int c = cg * CG + cl;
    out[(((size_t)k * C_ + c) * PH_ + ph) * PW_ + pw] = acc * 0.25f;
}

extern "C" void kernel_launch(void* const* d_in, const int* in_sizes, int n_in,
                              void* d_out, int out_size, void* d_ws, size_t ws_size,
                              hipStream_t stream) {
    const float* features = (const float*)d_in[0];  // [2,256,64,64]
    const float* boxes    = (const float*)d_in[1];  // [64,5]
    const float* masks    = (const float*)d_in[2];  // [64,256,64,64]
    float* out            = (float*)d_out;          // [64,256,7,7]

    dim3 grid(K_, C_ / CG);   // 64 x 128 blocks
    dim3 block(BT);
    masked_roialign_h16<<<grid, block, 0, stream>>>(features, boxes, masks, out);
}

// Round 6
// 320.011 us; speedup vs baseline: 1.1101x; 1.0386x over previous
//
#include <hip/hip_runtime.h>
#include <hip/hip_bf16.h>
#include <hip/hip_fp16.h>

// MaskedRoIAlign: out[k,c,ph,pw] = mean over SR*SR bilinear samples of
// (features[b_k] * masks[k]) with torchvision RoIAlign edge handling.
// N=2, C=256, H=W=64, K=64, PH=PW=7, SCALE=0.25, SR=2. Output fp32.
//
// R5: R4 (fp16-LDS product, nontemporal mask stream) +
//  - CG=4 channels/block, BT=256: 4096 blocks (half per-block overhead),
//    8x16B loads in flight per phase-1 iteration. 32KB LDS -> 5 blocks/CU
//    x 4 waves = 20 waves/CU (same occupancy as R4).
//  - Sparse row mode: when nrows > 28, the 14 sample-ys touch <= 28 rows
//    (bin_h > 2 leaves gaps); load exactly those rows instead of the whole
//    contiguous range. Saves ~16% of the ~97MB mask HBM stream. Duplicate
//    slots write identical bytes to the same LDS address (benign race).
// Kernel streaming floor ~15-20us; bench dur_us carries ~300us fixed
// harness reset (1.07GB ws poison fill ~161us + ~264MB input restore).

constexpr int N_ = 2, C_ = 256, H_ = 64, W_ = 64;
constexpr int K_ = 64, PH_ = 7, PW_ = 7, SR_ = 2;
constexpr float SCALE_ = 0.25f;
constexpr int CG = 4;          // channels per block
constexpr int BT = 256;        // 4 waves; phase2: wave i -> channel i
constexpr int HW = H_ * W_;

typedef float vf4 __attribute__((ext_vector_type(4)));

__global__ __launch_bounds__(BT)
void masked_roialign_r5(const float* __restrict__ features,
                        const float* __restrict__ boxes,
                        const float* __restrict__ masks,
                        float* __restrict__ out) {
    __shared__ __half prod[CG][HW];        // 4 x 8 KB = 32 KB

    const int k  = blockIdx.x;             // box
    const int cg = blockIdx.y;             // channel group of CG
    const int t  = threadIdx.x;

    // Box parameters (uniform per block).
    const float* bx = boxes + k * 5;
    const int   b  = (int)bx[0];
    const float x1 = bx[1] * SCALE_;
    const float y1 = bx[2] * SCALE_;
    const float x2 = bx[3] * SCALE_;
    const float y2 = bx[4] * SCALE_;
    const float roi_w = fmaxf(x2 - x1, 1.0f);
    const float roi_h = fmaxf(y2 - y1, 1.0f);
    const float bin_w = roi_w * (1.0f / PW_);
    const float bin_h = roi_h * (1.0f / PH_);

    // Contiguous row range covering all clamped sample rows + neighbors.
    const float ymin_c = fminf(fmaxf(y1 + 0.25f * bin_h, 0.0f), (float)(H_ - 1));
    const float ymax_c = fminf(fmaxf(y1 + 6.75f * bin_h, 0.0f), (float)(H_ - 1));
    const int ylo   = (int)ymin_c;
    const int yhi   = min((int)ymax_c + 1, H_ - 1);
    const int nrows = yhi - ylo + 1;                 // 1..64

    // Phase 1: stream needed rows; fp16 product -> LDS.
    // Thread map: tx = float4 column (16 lanes), ty = row slot (16 lanes).
    {
        const int tx = (t & 15) << 2;                // float column 0..60
        const int ty = t >> 4;                       // 0..15
        const int c0 = cg * CG;
        const float* fb = features + ((size_t)b * C_ + c0) * HW;
        const float* mb = masks    + ((size_t)k * C_ + c0) * HW;
        const bool sparse = (nrows > 2 * PH_ * SR_); // touched rows <= 28
        const int  nslots = sparse ? 2 * PH_ * SR_ : nrows;

        for (int slot = ty; slot < nslots; slot += 16) {
            int row;
            if (sparse) {
                // slot -> (sample s = slot/2, lower/upper row)
                const int   s  = slot >> 1;          // 0..13
                const int   ph = s >> 1;             // 0..6
                const int   iy = s & 1;
                const float y  = y1 + ((float)ph + ((float)iy + 0.5f) * 0.5f) * bin_h;
                const float yc = fminf(fmaxf(y, 0.0f), (float)(H_ - 1));
                const int   yl = (int)yc;
                row = (slot & 1) ? min(yl + 1, H_ - 1) : yl;
            } else {
                row = ylo + slot;
            }
            const int off = row * W_ + tx;
            vf4 fv[CG], mv[CG];
#pragma unroll
            for (int cl = 0; cl < CG; ++cl) {
                fv[cl] = *(const vf4*)(fb + (size_t)cl * HW + off);
                mv[cl] = __builtin_nontemporal_load((const vf4*)(mb + (size_t)cl * HW + off));
            }
#pragma unroll
            for (int cl = 0; cl < CG; ++cl) {
                __half2* d = (__half2*)&prod[cl][off];
                d[0] = __floats2half2_rn(fv[cl].x * mv[cl].x, fv[cl].y * mv[cl].y);
                d[1] = __floats2half2_rn(fv[cl].z * mv[cl].z, fv[cl].w * mv[cl].w);
            }
        }
    }
    __syncthreads();

    // Phase 2: wave cl handles channel cg*CG+cl; lane = output bin (49/64).
    const int cl  = t >> 6;                          // 0..3
    const int bin = t & 63;
    if (bin >= PH_ * PW_) return;
    const int ph = bin / PW_;
    const int pw = bin - ph * PW_;

    const __half* __restrict__ p = prod[cl];

    float acc = 0.0f;
#pragma unroll
    for (int iy = 0; iy < SR_; ++iy) {
        const float y  = y1 + ((float)ph + ((float)iy + 0.5f) * 0.5f) * bin_h;
        const bool  vy = (y >= -1.0f) && (y <= (float)H_);
        const float yc = fminf(fmaxf(y, 0.0f), (float)(H_ - 1));
        const int   yl = (int)yc;
        const int   yh = min(yl + 1, H_ - 1);
        const float ly = yc - (float)yl;
        const float hy = 1.0f - ly;
        const int   rl = yl * W_;
        const int   rh = yh * W_;
#pragma unroll
        for (int ix = 0; ix < SR_; ++ix) {
            const float x  = x1 + ((float)pw + ((float)ix + 0.5f) * 0.5f) * bin_w;
            const bool  vx = (x >= -1.0f) && (x <= (float)W_);
            const float xc = fminf(fmaxf(x, 0.0f), (float)(W_ - 1));
            const int   xl = (int)xc;
            const int   xh = min(xl + 1, W_ - 1);
            const float lx = xc - (float)xl;
            const float hx = 1.0f - lx;

            const float v00 = __half2float(p[rl + xl]);
            const float v01 = __half2float(p[rl + xh]);
            const float v10 = __half2float(p[rh + xl]);
            const float v11 = __half2float(p[rh + xh]);
            const float val = hy * hx * v00 + hy * lx * v01
                            + ly * hx * v10 + ly * lx * v11;
            acc += (vy && vx) ? val : 0.0f;
        }
    }
    const int c = cg * CG + cl;
    out[(((size_t)k * C_ + c) * PH_ + ph) * PW_ + pw] = acc * 0.25f;
}

extern "C" void kernel_launch(void* const* d_in, const int* in_sizes, int n_in,
                              void* d_out, int out_size, void* d_ws, size_t ws_size,
                              hipStream_t stream) {
    const float* features = (const float*)d_in[0];  // [2,256,64,64]
    const float* boxes    = (const float*)d_in[1];  // [64,5]
    const float* masks    = (const float*)d_in[2];  // [64,256,64,64]
    float* out            = (float*)d_out;          // [64,256,7,7]

    dim3 grid(K_, C_ / CG);   // 64 x 64 blocks
    dim3 block(BT);
    masked_roialign_r5<<<grid, block, 0, stream>>>(features, boxes, masks, out);
}